// Round 3
// baseline (54.417 us; speedup 1.0000x reference)
//
#include <hip/hip_runtime.h>
#include <hip/hip_bf16.h>

// out[b,i,j,o] = (x[b,min]·M_lo[o] + s_lo[o]) + (x[b,max]·M_hi[o] + s_hi[o])
// where M_lo[o] = W1^T Wc[o,:100], M_hi[o] = W1^T Wc[o,100:],
//       s_lo[o] = b1·Wc[o,:100] + bc[o], s_hi[o] = b1·Wc[o,100:].

#define NA 13
#define DM 512
#define NOH 8   // 4 outputs x {lo,hi}
#define NBLK 2048

typedef float fv4 __attribute__((ext_vector_type(4)));

__global__ __launch_bounds__(128) void precompute_M(
    const float* __restrict__ W1, const float* __restrict__ b1,
    const float* __restrict__ Wc, const float* __restrict__ bc,
    float* __restrict__ M, float* __restrict__ s) {
    int oh = blockIdx.x;          // 0..7: oh = half*4 + o
    int o = oh & 3, half = oh >> 2;
    int d = blockIdx.y * 128 + threadIdx.x;   // 0..511
    const float* wc = Wc + o * 200 + half * 100;
    float acc = 0.f;
    for (int c = 0; c < 100; ++c)
        acc = fmaf(wc[c], W1[c * DM + d], acc);
    M[oh * DM + d] = acc;
    if (d == 0) {
        float sv = (half == 0) ? bc[o] : 0.f;
        for (int c = 0; c < 100; ++c) sv = fmaf(wc[c], b1[c], sv);
        s[oh] = sv;
    }
}

__global__ __launch_bounds__(256, 4) void edge_main(
    const float* __restrict__ x, const float* __restrict__ M,
    const float* __restrict__ s, float* __restrict__ out, int B) {
    const int lane = threadIdx.x & 63;
    const int wave = threadIdx.x >> 6;

    // Per-lane M slices: lane covers d = lane*4..+3 and d = 256+lane*4..+3
    fv4 mA[NOH], mB[NOH];
#pragma unroll
    for (int oh = 0; oh < NOH; ++oh) {
        mA[oh] = *(const fv4*)(M + oh * DM + lane * 4);
        mB[oh] = *(const fv4*)(M + oh * DM + 256 + lane * 4);
    }
    const float s_lane = s[lane & 7];

    const bool m1 = (lane & 1) != 0;
    const bool m2 = (lane & 2) != 0;
    const bool m4 = (lane & 4) != 0;

    __shared__ float G[2][NA][NOH];
    int p = 0;

    for (int b = blockIdx.x; b < B; b += NBLK) {
        const float* xb = x + (size_t)b * (NA * DM);
#pragma unroll
        for (int k = 0; k < 4; ++k) {
            const int a = wave + 4 * k;
            if (a < NA) {
                fv4 xA = __builtin_nontemporal_load(
                    (const fv4*)(xb + a * DM + lane * 4));
                fv4 xB = __builtin_nontemporal_load(
                    (const fv4*)(xb + a * DM + 256 + lane * 4));
                float acc[NOH];
#pragma unroll
                for (int oh = 0; oh < NOH; ++oh) {
                    float v = xA.x * mA[oh].x;
                    v = fmaf(xA.y, mA[oh].y, v);
                    v = fmaf(xA.z, mA[oh].z, v);
                    v = fmaf(xA.w, mA[oh].w, v);
                    v = fmaf(xB.x, mB[oh].x, v);
                    v = fmaf(xB.y, mB[oh].y, v);
                    v = fmaf(xB.z, mB[oh].z, v);
                    v = fmaf(xB.w, mB[oh].w, v);
                    acc[oh] = v;
                }
                // transpose-reduce: 3 merge steps leave lane l holding
                // oh=(l&7)'s partial; 3 butterflies finish the 64 lanes.
                float r1[4];
#pragma unroll
                for (int q = 0; q < 4; ++q) {
                    float keep = m1 ? acc[2 * q + 1] : acc[2 * q];
                    float send = m1 ? acc[2 * q]     : acc[2 * q + 1];
                    r1[q] = keep + __shfl_xor(send, 1, 64);
                }
                float r2[2];
#pragma unroll
                for (int q = 0; q < 2; ++q) {
                    float keep = m2 ? r1[2 * q + 1] : r1[2 * q];
                    float send = m2 ? r1[2 * q]     : r1[2 * q + 1];
                    r2[q] = keep + __shfl_xor(send, 2, 64);
                }
                float keep = m4 ? r2[1] : r2[0];
                float send = m4 ? r2[0] : r2[1];
                float t = keep + __shfl_xor(send, 4, 64);
                t += __shfl_xor(t, 8, 64);
                t += __shfl_xor(t, 16, 64);
                t += __shfl_xor(t, 32, 64);
                if (lane < NOH) G[p][a][lane] = t + s_lane;
            }
        }
        __syncthreads();
        // 13*13 pairs, one float4 (4 outputs) per thread, coalesced.
        // Double-buffered G: next iteration's compute writes G[p^1], so no
        // second barrier is needed before it.
        const int t = threadIdx.x;
        if (t < NA * NA) {
            int i = t / NA, j = t % NA;
            int lo = i < j ? i : j;
            int hi = i < j ? j : i;
            fv4 v;
            v.x = G[p][lo][0] + G[p][hi][4];
            v.y = G[p][lo][1] + G[p][hi][5];
            v.z = G[p][lo][2] + G[p][hi][6];
            v.w = G[p][lo][3] + G[p][hi][7];
            __builtin_nontemporal_store(
                v, (fv4*)(out + (size_t)b * (NA * NA * 4)) + t);
        }
        p ^= 1;
    }
}

extern "C" void kernel_launch(void* const* d_in, const int* in_sizes, int n_in,
                              void* d_out, int out_size, void* d_ws, size_t ws_size,
                              hipStream_t stream) {
    const float* x  = (const float*)d_in[0];
    const float* W1 = (const float*)d_in[1];
    const float* b1 = (const float*)d_in[2];
    const float* Wc = (const float*)d_in[3];
    const float* bc = (const float*)d_in[4];
    float* out = (float*)d_out;
    const int B = in_sizes[0] / (NA * DM);   // 8192

    float* M = (float*)d_ws;            // 8*512 floats = 16 KB
    float* s = M + NOH * DM;            // 8 floats

    precompute_M<<<dim3(8, 4), 128, 0, stream>>>(W1, b1, Wc, bc, M, s);
    edge_main<<<NBLK, 256, 0, stream>>>(x, M, s, out, B);
}

// Round 4
// 47.596 us; speedup vs baseline: 1.1433x; 1.1433x over previous
//
#include <hip/hip_runtime.h>
#include <hip/hip_bf16.h>

// out[b,i,j,o] = (x[b,min]·M_lo[o] + s_lo[o]) + (x[b,max]·M_hi[o] + s_hi[o])
// where M_lo[o] = W1^T Wc[o,:100], M_hi[o] = W1^T Wc[o,100:],
//       s_lo[o] = b1·Wc[o,:100] + bc[o], s_hi[o] = b1·Wc[o,100:].

#define NA 13
#define DM 512
#define NOH 8   // 4 outputs x {lo,hi}

typedef float fv4 __attribute__((ext_vector_type(4)));

__global__ __launch_bounds__(128) void precompute_M(
    const float* __restrict__ W1, const float* __restrict__ b1,
    const float* __restrict__ Wc, const float* __restrict__ bc,
    float* __restrict__ M, float* __restrict__ s) {
    int oh = blockIdx.x;          // 0..7: oh = half*4 + o
    int o = oh & 3, half = oh >> 2;
    int d = blockIdx.y * 128 + threadIdx.x;   // 0..511
    const float* wc = Wc + o * 200 + half * 100;
    float acc = 0.f;
    for (int c = 0; c < 100; ++c)
        acc = fmaf(wc[c], W1[c * DM + d], acc);
    M[oh * DM + d] = acc;
    if (d == 0) {
        float sv = (half == 0) ? bc[o] : 0.f;
        for (int c = 0; c < 100; ++c) sv = fmaf(wc[c], b1[c], sv);
        s[oh] = sv;
    }
}

__global__ __launch_bounds__(256) void edge_main(
    const float* __restrict__ x, const float* __restrict__ M,
    const float* __restrict__ s, float* __restrict__ out) {
    const int b = blockIdx.x;
    const int lane = threadIdx.x & 63;
    const int wave = threadIdx.x >> 6;

    const float* xb = x + (size_t)b * (NA * DM);

    // Issue ALL of this wave's x loads first (wave 0: rows {0,4,8,12};
    // waves 1-3: {w, w+4, w+8}) — 6-8 x 16B loads in flight per wave
    // before any dependent compute. `a < NA` is wave-uniform.
    fv4 xA[4], xB[4];
#pragma unroll
    for (int k = 0; k < 4; ++k) {
        const int a = wave + 4 * k;
        if (a < NA) {
            xA[k] = *(const fv4*)(xb + a * DM + lane * 4);
            xB[k] = *(const fv4*)(xb + a * DM + 256 + lane * 4);
        }
    }

    // Per-lane M slices: lane covers d = lane*4..+3 and d = 256+lane*4..+3
    fv4 mA[NOH], mB[NOH];
#pragma unroll
    for (int oh = 0; oh < NOH; ++oh) {
        mA[oh] = *(const fv4*)(M + oh * DM + lane * 4);
        mB[oh] = *(const fv4*)(M + oh * DM + 256 + lane * 4);
    }
    const float s_lane = s[lane & 7];

    const bool m1 = (lane & 1) != 0;
    const bool m2 = (lane & 2) != 0;
    const bool m4 = (lane & 4) != 0;

    __shared__ float G[NA][NOH];

#pragma unroll
    for (int k = 0; k < 4; ++k) {
        const int a = wave + 4 * k;
        if (a < NA) {
            float acc[NOH];
#pragma unroll
            for (int oh = 0; oh < NOH; ++oh) {
                float v = xA[k].x * mA[oh].x;
                v = fmaf(xA[k].y, mA[oh].y, v);
                v = fmaf(xA[k].z, mA[oh].z, v);
                v = fmaf(xA[k].w, mA[oh].w, v);
                v = fmaf(xB[k].x, mB[oh].x, v);
                v = fmaf(xB[k].y, mB[oh].y, v);
                v = fmaf(xB[k].z, mB[oh].z, v);
                v = fmaf(xB[k].w, mB[oh].w, v);
                acc[oh] = v;
            }
            // transpose-reduce: 3 merge steps leave lane l holding oh=(l&7)'s
            // 8-lane partial; 3 butterflies finish the 64 lanes.
            float r1[4];
#pragma unroll
            for (int q = 0; q < 4; ++q) {
                float keep = m1 ? acc[2 * q + 1] : acc[2 * q];
                float send = m1 ? acc[2 * q]     : acc[2 * q + 1];
                r1[q] = keep + __shfl_xor(send, 1, 64);
            }
            float r2[2];
#pragma unroll
            for (int q = 0; q < 2; ++q) {
                float keep = m2 ? r1[2 * q + 1] : r1[2 * q];
                float send = m2 ? r1[2 * q]     : r1[2 * q + 1];
                r2[q] = keep + __shfl_xor(send, 2, 64);
            }
            float keep = m4 ? r2[1] : r2[0];
            float send = m4 ? r2[0] : r2[1];
            float t = keep + __shfl_xor(send, 4, 64);
            t += __shfl_xor(t, 8, 64);
            t += __shfl_xor(t, 16, 64);
            t += __shfl_xor(t, 32, 64);
            if (lane < NOH) G[a][lane] = t + s_lane;
        }
    }
    __syncthreads();

    // 13*13 pairs, one float4 (4 outputs) per thread, coalesced
    const int t = threadIdx.x;
    if (t < NA * NA) {
        int i = t / NA, j = t % NA;
        int lo = i < j ? i : j;
        int hi = i < j ? j : i;
        fv4 v;
        v.x = G[lo][0] + G[hi][4];
        v.y = G[lo][1] + G[hi][5];
        v.z = G[lo][2] + G[hi][6];
        v.w = G[lo][3] + G[hi][7];
        ((fv4*)(out + (size_t)b * (NA * NA * 4)))[t] = v;
    }
}

extern "C" void kernel_launch(void* const* d_in, const int* in_sizes, int n_in,
                              void* d_out, int out_size, void* d_ws, size_t ws_size,
                              hipStream_t stream) {
    const float* x  = (const float*)d_in[0];
    const float* W1 = (const float*)d_in[1];
    const float* b1 = (const float*)d_in[2];
    const float* Wc = (const float*)d_in[3];
    const float* bc = (const float*)d_in[4];
    float* out = (float*)d_out;
    const int B = in_sizes[0] / (NA * DM);   // 8192

    float* M = (float*)d_ws;            // 8*512 floats = 16 KB
    float* s = M + NOH * DM;            // 8 floats

    precompute_M<<<dim3(8, 4), 128, 0, stream>>>(W1, b1, Wc, bc, M, s);
    edge_main<<<B, 256, 0, stream>>>(x, M, s, out);
}